// Round 6
// baseline (386.588 us; speedup 1.0000x reference)
//
#include <hip/hip_runtime.h>
#include <hip/hip_bf16.h>
#include <cstdint>
#include <cstddef>

#define DM 1024
#define NH 16
#define DH 64
#define BB 2
#define TQ 2048
#define TCACHE 2048
#define TKTOT 4096
#define MROWS 4096

typedef __attribute__((ext_vector_type(8))) short bf16x8;
typedef __attribute__((ext_vector_type(4))) float f32x4;
typedef __attribute__((ext_vector_type(16))) float f32x16;

// pack two f32 -> two bf16 in one dword (RNE). gfx950 has NO builtin for
// cvt_pk_bf16 (m240) -- must use inline asm; the software path is ~12 VALU ops.
__device__ __forceinline__ unsigned pk2(float a, float b) {
  unsigned r;
  asm("v_cvt_pk_bf16_f32 %0, %1, %2" : "=v"(r) : "v"(a), "v"(b));
  return r;
}

__device__ __forceinline__ short f2bf(float f) {
  return (short)(unsigned short)pk2(f, f);
}

__device__ __forceinline__ uint2 pk4(float x, float y, float z, float w) {
  uint2 r;
  r.x = pk2(x, y);
  r.y = pk2(z, w);
  return r;
}

__device__ __forceinline__ float bf2f(short s) {
  union { unsigned u; float f; } v;
  v.u = ((unsigned)(unsigned short)s) << 16;
  return v.f;
}

__device__ __forceinline__ float exp2fast(float x) {
#if __has_builtin(__builtin_amdgcn_exp2f)
  return __builtin_amdgcn_exp2f(x);
#else
  return exp2f(x);
#endif
}

// v_permlane32_swap_b32: a' = {a.lo, b.lo}, b' = {a.hi, b.hi} (lane halves)
__device__ __forceinline__ void plswap(unsigned& a, unsigned& b) {
  asm volatile("v_permlane32_swap_b32 %0, %1" : "+v"(a), "+v"(b));
}

// async global->LDS, 16B/lane. LDS dest must be wave-uniform base + lane*16;
// swizzle goes on the GLOBAL address only (m104/m108).
__device__ __forceinline__ void gld_lds16(const short* g, short* l) {
  __builtin_amdgcn_global_load_lds(
      (const __attribute__((address_space(1))) void*)((uintptr_t)g),
      (__attribute__((address_space(3))) void*)((uintptr_t)l), 16, 0, 0);
}

// ---------- prep kernel: x conversion + W transpose only ----------
// roles by linear blockIdx.x (all 256 threads):
//   [0,4096)      cvt_x:       x f32 -> xb bf16
//   [4096,8192)   transpose_w: W f32 [K][N] -> Wt bf16 [N][K] (4 weights)
__global__ __launch_bounds__(256) void k_prep(
    const float* __restrict__ x, short* __restrict__ xb,
    const float* __restrict__ W0, const float* __restrict__ W1,
    const float* __restrict__ W2, const float* __restrict__ W3,
    short* __restrict__ Wt) {
  __shared__ short lds[32 * 33];
  const int bid = (int)blockIdx.x;
  if (bid < 4096) {
    const size_t i = (size_t)bid * 256 + threadIdx.x;
    const float4 v = ((const float4*)x)[i];
    *(uint2*)(((short4*)xb) + i) = pk4(v.x, v.y, v.z, v.w);
  } else {
    const int local = bid - 4096;
    const int bx = local & 31, by = (local >> 5) & 31, bz = local >> 10;
    short (*tile)[33] = (short(*)[33])lds;
    const float* W = (bz == 0) ? W0 : (bz == 1) ? W1 : (bz == 2) ? W2 : W3;
    short* dst = Wt + (size_t)bz * DM * DM;
    const int k0 = by * 32, n0 = bx * 32;
    const int tx = threadIdx.x & 31, ty = threadIdx.x >> 5;
#pragma unroll
    for (int r = 0; r < 4; r++) {
      const int k = ty + r * 8;
      tile[k][tx] = f2bf(W[(size_t)(k0 + k) * DM + n0 + tx]);
    }
    __syncthreads();
#pragma unroll
    for (int r = 0; r < 4; r++) {
      const int n = ty + r * 8;
      dst[(size_t)(n0 + n) * DM + k0 + tx] = tile[tx][n];
    }
  }
}

// ---------- fused QKV GEMM + KV-cache conversion ----------
// roles by blockIdx.x:
//   [0,768)       GEMM 128x128, BK=32, dbuf global_load_lds (z = bid>>8: Q/K/V)
//   [768,4864)    kc f32 -> Kb bf16 (cache part; new part written by z==1 blocks)
//   [4864,5888)   vc f32 -> Vtb bf16 [dh][t] (cache part)
// copy blocks are pure streaming and backfill under the compute-bound GEMM
// blocks (3/CU), same complementary-pipe trick as attn+expand.
__global__ __launch_bounds__(256) void k_qkv(
    const short* __restrict__ A, const short* __restrict__ Bt,
    const float* __restrict__ b0, const float* __restrict__ b1, const float* __restrict__ b2,
    short* __restrict__ Qb, short* __restrict__ Kb, short* __restrict__ Vtb,
    const float* __restrict__ kc, const float* __restrict__ vc) {
  __shared__ short SH[16384];  // 32KB: GEMM sA[2]+sB[2]; vc-copy tile
  const int bid = (int)blockIdx.x;
  if (bid < 768) {
    const int z = bid >> 8;
    const int by = (bid >> 3) & 31;
    const int bx = bid & 7;
    const short* Bz = Bt + (size_t)z * DM * DM;
    const float* bias = (z == 0) ? b0 : (z == 1 ? b1 : b2);

    const int m0 = by * 128;
    const int n0 = bx * 128;
    const int tid = threadIdx.x;
    const int wv = tid >> 6;
    const int lane = tid & 63;
    const int quad = lane >> 4;
    const int l16 = lane & 15;
    const int wm = (wv >> 1) * 64;
    const int wn = (wv & 1) * 64;

    const f32x4 zero = {0.f, 0.f, 0.f, 0.f};
    f32x4 acc[4][4];
#pragma unroll
    for (int i = 0; i < 4; i++)
#pragma unroll
      for (int j = 0; j < 4; j++) acc[i][j] = zero;

    // sA: SH bytes [0,16384) (2 bufs x 8KB); sB: bytes [16384,32768)
    const int sw = (quad ^ ((l16 >> 1) & 3)) << 4;
    const int afo = (wm + l16) * 64 + sw;
    const int bfo = (wn + l16) * 64 + sw;

#define STAGEG(k0_, b_)                                                              \
    do {                                                                             \
      _Pragma("unroll") for (int s = 0; s < 2; s++) {                                \
        const int c = tid + s * 256;                                                 \
        const int row = c >> 2, cs = c & 3;                                          \
        const int gc = cs ^ ((row >> 1) & 3);                                        \
        gld_lds16(A + (size_t)(m0 + row) * DM + (k0_) + gc * 8,                      \
                  SH + (b_) * 4096 + c * 8);                                         \
        gld_lds16(Bz + (size_t)(n0 + row) * DM + (k0_) + gc * 8,                     \
                  SH + 8192 + (b_) * 4096 + c * 8);                                  \
      }                                                                              \
    } while (0)

    STAGEG(0, 0);
    __syncthreads();
    int buf = 0;
    for (int k0 = 0; k0 < DM; k0 += 32) {
      if (k0 + 32 < DM) STAGEG(k0 + 32, buf ^ 1);
      const char* Ab = (const char*)SH + buf * 8192;
      const char* Bb = (const char*)SH + 16384 + buf * 8192;
      bf16x8 af[4], bfv[4];
#pragma unroll
      for (int i = 0; i < 4; i++) af[i] = *(const bf16x8*)(Ab + afo + i * 1024);
#pragma unroll
      for (int j = 0; j < 4; j++) bfv[j] = *(const bf16x8*)(Bb + bfo + j * 1024);
      __builtin_amdgcn_s_setprio(1);
#pragma unroll
      for (int i = 0; i < 4; i++)
#pragma unroll
        for (int j = 0; j < 4; j++)
          acc[i][j] = __builtin_amdgcn_mfma_f32_16x16x32_bf16(af[i], bfv[j], acc[i][j], 0, 0, 0);
      __builtin_amdgcn_s_setprio(0);
      __syncthreads();
      buf ^= 1;
    }
#undef STAGEG

#pragma unroll
    for (int i = 0; i < 4; i++) {
#pragma unroll
      for (int j = 0; j < 4; j++) {
        const int gn = n0 + wn + j * 16 + l16;
        const float bb = bias[gn];
#pragma unroll
        for (int r = 0; r < 4; r++) {
          const int gm = m0 + wm + i * 16 + quad * 4 + r;
          const float v = acc[i][j][r] + bb;
          const int b_ = gm >> 11, t = gm & 2047;
          const int h_ = gn >> 6, dh = gn & 63;
          if (z == 0) {
            // fold softmax scale AND log2(e): 0.125 * 1.4426950409
            Qb[(((size_t)(b_ * NH + h_)) * TQ + t) * DH + dh] = f2bf(v * 0.18033688011f);
          } else if (z == 1) {
            Kb[(((size_t)(b_ * NH + h_)) * TKTOT + TCACHE + t) * DH + dh] = f2bf(v);
          } else {
            Vtb[(((size_t)(b_ * NH + h_)) * DH + dh) * TKTOT + TCACHE + t] = f2bf(v);
          }
        }
      }
    }
  } else if (bid < 4864) {
    // kc copy role
    const size_t i = (size_t)(bid - 768) * 256 + threadIdx.x;
    const float4 v = ((const float4*)kc)[i];
    const size_t e = i * 4;
    const int dh = (int)(e & 63);
    const int t = (int)((e >> 6) & 2047);
    const int bh = (int)(e >> 17);
    *(uint2*)(Kb + ((size_t)bh * TKTOT + t) * DH + dh) = pk4(v.x, v.y, v.z, v.w);
  } else {
    // vc copy role (transpose to Vt[dh][t])
    const int local = bid - 4864;
    const int bh = local >> 5;
    const int t0 = (local & 31) * 64;
    short (*tile)[65] = (short(*)[65])SH;
    const int tx = threadIdx.x & 15, ty = threadIdx.x >> 4;
    const float* src = vc + ((size_t)bh * TCACHE + t0) * DH;
#pragma unroll
    for (int r = 0; r < 4; r++) {
      const int t = ty + r * 16;
      const float4 v = *(const float4*)(src + (size_t)t * DH + tx * 4);
      tile[tx * 4 + 0][t] = f2bf(v.x);
      tile[tx * 4 + 1][t] = f2bf(v.y);
      tile[tx * 4 + 2][t] = f2bf(v.z);
      tile[tx * 4 + 3][t] = f2bf(v.w);
    }
    __syncthreads();
    short* vt = Vtb + (size_t)bh * DH * TKTOT + t0;
#pragma unroll
    for (int r = 0; r < 4; r++) {
      const int dh = ty + r * 16;
      short4 o;
      o.x = tile[dh][tx * 4 + 0];
      o.y = tile[dh][tx * 4 + 1];
      o.z = tile[dh][tx * 4 + 2];
      o.w = tile[dh][tx * 4 + 3];
      *(short4*)(vt + (size_t)dh * TKTOT + tx * 4) = o;
    }
  }
}

// ---------- proj GEMM: out = AOb * Wo^T + bo (f32 output) ----------
__global__ __launch_bounds__(256) void k_gemm(
    const short* __restrict__ A, const short* __restrict__ Bt,
    const float* __restrict__ bias, float* __restrict__ fdst) {
  __shared__ short sA[2][128 * 32];
  __shared__ short sB[2][128 * 32];

  const int m0 = blockIdx.y * 128;
  const int n0 = blockIdx.x * 128;
  const int tid = threadIdx.x;
  const int wv = tid >> 6;
  const int lane = tid & 63;
  const int quad = lane >> 4;
  const int l16 = lane & 15;
  const int wm = (wv >> 1) * 64;
  const int wn = (wv & 1) * 64;

  const f32x4 zero = {0.f, 0.f, 0.f, 0.f};
  f32x4 acc[4][4];
#pragma unroll
  for (int i = 0; i < 4; i++)
#pragma unroll
    for (int j = 0; j < 4; j++) acc[i][j] = zero;

  const int sw = (quad ^ ((l16 >> 1) & 3)) << 4;
  const int afo = (wm + l16) * 64 + sw;
  const int bfo = (wn + l16) * 64 + sw;

#define STAGEG(k0_, b_)                                                         \
  do {                                                                          \
    _Pragma("unroll") for (int s = 0; s < 2; s++) {                             \
      const int c = tid + s * 256;                                              \
      const int row = c >> 2, cs = c & 3;                                       \
      const int gc = cs ^ ((row >> 1) & 3);                                     \
      gld_lds16(A + (size_t)(m0 + row) * DM + (k0_) + gc * 8, &sA[b_][c * 8]);  \
      gld_lds16(Bt + (size_t)(n0 + row) * DM + (k0_) + gc * 8, &sB[b_][c * 8]); \
    }                                                                           \
  } while (0)

  STAGEG(0, 0);
  __syncthreads();
  int buf = 0;
  for (int k0 = 0; k0 < DM; k0 += 32) {
    if (k0 + 32 < DM) STAGEG(k0 + 32, buf ^ 1);
    const char* Ab = (const char*)&sA[0][0] + buf * 8192;
    const char* Bb = (const char*)&sB[0][0] + buf * 8192;
    bf16x8 af[4], bfv[4];
#pragma unroll
    for (int i = 0; i < 4; i++) af[i] = *(const bf16x8*)(Ab + afo + i * 1024);
#pragma unroll
    for (int j = 0; j < 4; j++) bfv[j] = *(const bf16x8*)(Bb + bfo + j * 1024);
    __builtin_amdgcn_s_setprio(1);
#pragma unroll
    for (int i = 0; i < 4; i++)
#pragma unroll
      for (int j = 0; j < 4; j++)
        acc[i][j] = __builtin_amdgcn_mfma_f32_16x16x32_bf16(af[i], bfv[j], acc[i][j], 0, 0, 0);
    __builtin_amdgcn_s_setprio(0);
    __syncthreads();
    buf ^= 1;
  }
#undef STAGEG

#pragma unroll
  for (int i = 0; i < 4; i++) {
#pragma unroll
    for (int j = 0; j < 4; j++) {
      const int gn = n0 + wn + j * 16 + l16;
      const float bb = bias[gn];
#pragma unroll
      for (int r = 0; r < 4; r++) {
        const int gm = m0 + wm + i * 16 + quad * 4 + r;
        fdst[(size_t)gm * DM + gn] = acc[i][j][r] + bb;
      }
    }
  }
}

// ---------- fused attention + expand ----------
// roles by blockIdx.x:
//   [0,512)       flash attention, QBLK=128, NO LDS staging, NO barriers:
//                 K+V per (b,h) = 1 MB bf16 -> L2/L3-resident (m169: don't stage
//                 what cache-fits). Each lane reads its K fragment (row j0+l32,
//                 16B chunks) and V fragment (Vt row l32, 16B chunks) straight
//                 from global into registers; the 4 waves are fully independent
//                 (no lockstep, no vmcnt(0) drain). Softmax denominators
//                 broadcast through 512B of LDS at the end (same-wave ordering).
//   [512,8704)    expand_k: kF f32 from kc (cache, exact) / Kb bf16 (new)
//   [8704,10752)  expand_v: vF f32 from vc (cache) / Vtb transposed (new)
// LDS block size is now 9.2KB -> expand blocks pack densely and stream under
// the attention blocks' latency shadow.
__global__ __launch_bounds__(256, 2) void k_attn_expand(
    const short* __restrict__ Qb, const short* __restrict__ Kb,
    const short* __restrict__ Vtb, short* __restrict__ AOb,
    const float* __restrict__ kc, float* __restrict__ kF,
    const float* __restrict__ vc, float* __restrict__ vF) {
  __shared__ short SH[64 * 72];  // expand_v tile; attn uses first 512B for l-bcast

  const int bid = (int)blockIdx.x;
  if (bid < 512) {
    // ---------------- attention role ----------------
    const int y = bid >> 5;
    const int bh = bid & 31;
    const int qx = (y < 8) ? (15 - y) : (y - 8);  // pair long+short per CU
    const int q0 = qx * 128;
    const int tid = threadIdx.x;
    const int wq = tid >> 6;
    const int lane = tid & 63;
    const int l32 = lane & 31;
    const int h = lane >> 5;

    const int nkt = 2 * qx + 34;  // total key tiles for this q-block

    const short* Kg = Kb + (size_t)bh * TKTOT * DH;
    const short* Vtg = Vtb + (size_t)bh * DH * TKTOT;

    // per-lane row bases (+8h element offset folded in)
    const short* kr0 = Kg + (size_t)l32 * DH + 8 * h;
    const short* kr1 = Kg + (size_t)(l32 + 32) * DH + 8 * h;
    const short* vr0 = Vtg + (size_t)l32 * TKTOT + 8 * h;
    const short* vr1 = Vtg + (size_t)(l32 + 32) * TKTOT + 8 * h;

    // Q fragments straight from global: B-operand, lane holds q=l32, k=8h+i
    const short* Qrow = Qb + ((size_t)bh * TQ + q0 + wq * 32 + l32) * DH;
    bf16x8 qf[4];
#pragma unroll
    for (int s = 0; s < 4; s++) qf[s] = *(const bf16x8*)(Qrow + s * 16 + h * 8);

    const f32x16 zerov = {0, 0, 0, 0, 0, 0, 0, 0, 0, 0, 0, 0, 0, 0, 0, 0};
    f32x16 of0 = zerov;
    f32x16 of1 = zerov;
    float la = 0.f, lb = 0.f, lc = 0.f, ld = 0.f;

    for (int t = 0; t < nkt; t++) {
      const size_t kbase = (size_t)t * (64 * DH);  // K element offset of tile
      const size_t vbase = (size_t)t * 64;         // Vt column offset of tile

      // K fragments: lane reads rows j0+l32 / j0+32+l32, bytes 32ks+16h
      bf16x8 kf0[4], kf1[4];
#pragma unroll
      for (int ks = 0; ks < 4; ks++) {
        kf0[ks] = *(const bf16x8*)(kr0 + kbase + ks * 16);
        kf1[ks] = *(const bf16x8*)(kr1 + kbase + ks * 16);
      }

      // Sacc = K * Q^T : col(lane&31)=q, row(reg)=key = (r&3)+8*(r>>2)+4h (+32 blk1)
      f32x16 sacc0, sacc1;
      __builtin_amdgcn_s_setprio(1);
      sacc0 = __builtin_amdgcn_mfma_f32_32x32x16_bf16(kf0[0], qf[0], zerov, 0, 0, 0);
      sacc1 = __builtin_amdgcn_mfma_f32_32x32x16_bf16(kf1[0], qf[0], zerov, 0, 0, 0);
#pragma unroll
      for (int ks = 1; ks < 4; ks++) {
        sacc0 = __builtin_amdgcn_mfma_f32_32x32x16_bf16(kf0[ks], qf[ks], sacc0, 0, 0, 0);
        sacc1 = __builtin_amdgcn_mfma_f32_32x32x16_bf16(kf1[ks], qf[ks], sacc1, 0, 0, 0);
      }
      __builtin_amdgcn_s_setprio(0);

      // V fragments issued here: loads fly under the exp/pack VALU chain
      bf16x8 vf0[4], vf1[4];
#pragma unroll
      for (int ks = 0; ks < 4; ks++) {
        vf0[ks] = *(const bf16x8*)(vr0 + vbase + ks * 16);
        vf1[ks] = *(const bf16x8*)(vr1 + vbase + ks * 16);
      }

      if (t >= nkt - 2) {  // diagonal spans 2 tiles at QBLK=128
        const int qgl = q0 + wq * 32 + l32 + TCACHE;
        const int kb0 = t * 64 + 4 * h;
#pragma unroll
        for (int r = 0; r < 16; r++) {
          const int key = kb0 + (r & 3) + 8 * (r >> 2);
          if (key > qgl) sacc0[r] = -1e30f;
          if (key + 32 > qgl) sacc1[r] = -1e30f;
        }
      }
#pragma unroll
      for (int r = 0; r < 16; r++) {
        const float e0 = exp2fast(sacc0[r]);
        const float e1 = exp2fast(sacc1[r]);
        sacc0[r] = e0;
        sacc1[r] = e1;
        if ((r & 3) == 0) la += e0 + e1;
        else if ((r & 3) == 1) lb += e0 + e1;
        else if ((r & 3) == 2) lc += e0 + e1;
        else ld += e0 + e1;
      }

      // pack + lane-half swap -> PV A-operand: row(lane&31)=q, k=8h+i per kstep
      bf16x8 pa[4];
#pragma unroll
      for (int s = 0; s < 4; s++) {
        const int o = (s & 1) * 8;
        unsigned w0, w1, w2, w3;
        if (s < 2) {
          w0 = pk2(sacc0[o + 0], sacc0[o + 1]);
          w1 = pk2(sacc0[o + 2], sacc0[o + 3]);
          w2 = pk2(sacc0[o + 4], sacc0[o + 5]);
          w3 = pk2(sacc0[o + 6], sacc0[o + 7]);
        } else {
          w0 = pk2(sacc1[o + 0], sacc1[o + 1]);
          w1 = pk2(sacc1[o + 2], sacc1[o + 3]);
          w2 = pk2(sacc1[o + 4], sacc1[o + 5]);
          w3 = pk2(sacc1[o + 6], sacc1[o + 7]);
        }
        plswap(w0, w2);  // w0={lo,lo}, w2={hi,hi}
        plswap(w1, w3);
        union { unsigned u[4]; bf16x8 v; } pu;
        pu.u[0] = w0; pu.u[1] = w1; pu.u[2] = w2; pu.u[3] = w3;
        pa[s] = pu.v;
      }

      // O[q][dh] += P * V
      __builtin_amdgcn_s_setprio(1);
#pragma unroll
      for (int ks = 0; ks < 4; ks++) {
        of0 = __builtin_amdgcn_mfma_f32_32x32x16_bf16(pa[ks], vf0[ks], of0, 0, 0, 0);
        of1 = __builtin_amdgcn_mfma_f32_32x32x16_bf16(pa[ks], vf1[ks], of1, 0, 0, 0);
      }
      __builtin_amdgcn_s_setprio(0);
    }

    // ---- in-kernel normalize + bf16 output ----
    // per-wave LDS slice disjoint; same-wave ds_write->ds_read order is
    // lgkmcnt-enforced, no barrier needed.
    float* sLf = (float*)SH;
    const float l_lane = (la + lb) + (lc + ld);
    const float l_tot = l_lane + __shfl_xor(l_lane, 32);
    if (h == 0) sLf[wq * 32 + l32] = l_tot;
    const int b_ = bh >> 4, h_ = bh & 15;
#pragma unroll
    for (int r = 0; r < 16; r++) {
      const int row = (r & 3) + 8 * (r >> 2) + 4 * h;  // q within the wave's 32
      const float inv = 1.f / sLf[wq * 32 + row];
      const int qg = q0 + wq * 32 + row;
      short* d = AOb + ((size_t)(b_ * TQ + qg)) * DM + h_ * 64;
      d[l32] = f2bf(of0[r] * inv);
      d[32 + l32] = f2bf(of1[r] * inv);
    }
  } else if (bid < 8704) {
    // ---------------- expand_k role ----------------
    const size_t f4 = (size_t)(bid - 512) * 256 + threadIdx.x;
    const size_t e = f4 * 4;
    const int t = (int)((e >> 6) & 4095);
    float4 v;
    if (t < TCACHE) {
      const int dh = (int)(e & 63);
      const int bh = (int)(e >> 18);
      v = *(const float4*)(kc + ((size_t)(bh * TCACHE + t)) * DH + dh);
    } else {
      const short4 s = *(const short4*)(Kb + e);
      v.x = bf2f(s.x); v.y = bf2f(s.y); v.z = bf2f(s.z); v.w = bf2f(s.w);
    }
    *(float4*)(kF + e) = v;
  } else {
    // ---------------- expand_v role ----------------
    const int local = bid - 8704;
    const int tt = local & 63, bh = local >> 6;
    short* tile = SH;  // [64][72]
    if (tt < 32) {
#pragma unroll
      for (int k2 = 0; k2 < 4; k2++) {
        const int f = threadIdx.x + k2 * 256;
        const int trow = f >> 4, dh4 = f & 15;
        const size_t si = ((size_t)(bh * TCACHE) + tt * 64 + trow) * DH + dh4 * 4;
        const size_t di = ((size_t)(bh * TKTOT) + tt * 64 + trow) * DH + dh4 * 4;
        *(float4*)(vF + di) = *(const float4*)(vc + si);
      }
    } else {
      const int t0 = tt * 64;
#pragma unroll
      for (int k2 = 0; k2 < 4; k2++) {
        const int f = threadIdx.x + k2 * 256;
        const int dh = f >> 4, tc4 = f & 15;
        const short4 s = *(const short4*)(Vtb + ((size_t)(bh * DH + dh)) * TKTOT + t0 + tc4 * 4);
        *(short4*)(&tile[dh * 72 + tc4 * 4]) = s;
      }
      __syncthreads();
#pragma unroll
      for (int k2 = 0; k2 < 4; k2++) {
        const int f = threadIdx.x + k2 * 256;
        const int trow = f >> 4, dh4 = f & 15;
        float4 v;
        v.x = bf2f(tile[(dh4 * 4 + 0) * 72 + trow]);
        v.y = bf2f(tile[(dh4 * 4 + 1) * 72 + trow]);
        v.z = bf2f(tile[(dh4 * 4 + 2) * 72 + trow]);
        v.w = bf2f(tile[(dh4 * 4 + 3) * 72 + trow]);
        *(float4*)(vF + ((size_t)(bh * TKTOT) + t0 + trow) * DH + dh4 * 4) = v;
      }
    }
  }
}

// ---------- host ----------

extern "C" void kernel_launch(void* const* d_in, const int* in_sizes, int n_in,
                              void* d_out, int out_size, void* d_ws, size_t ws_size,
                              hipStream_t stream) {
  const float* x = (const float*)d_in[0];
  const float* kc = (const float*)d_in[1];
  const float* vc = (const float*)d_in[2];
  const float* Wq = (const float*)d_in[3];
  const float* bq = (const float*)d_in[4];
  const float* Wk = (const float*)d_in[5];
  const float* bk = (const float*)d_in[6];
  const float* Wv = (const float*)d_in[7];
  const float* bv = (const float*)d_in[8];
  const float* Wo = (const float*)d_in[9];
  const float* bo = (const float*)d_in[10];

  float* out = (float*)d_out;
  float* kF = out + (size_t)BB * TQ * DM;          // k output region (33.55 MB)
  float* vF = kF + (size_t)BB * NH * TKTOT * DH;   // v output region (33.55 MB)

  char* ws = (char*)d_ws;
  short* xb = (short*)ws;   ws += (size_t)MROWS * DM * 2;
  short* Wt = (short*)ws;   ws += (size_t)4 * DM * DM * 2;
  short* Qb = (short*)ws;   ws += (size_t)BB * NH * TQ * DH * 2;
  short* Kb = (short*)ws;   ws += (size_t)BB * NH * TKTOT * DH * 2;
  short* Vtb = (short*)ws;  ws += (size_t)BB * NH * TKTOT * DH * 2;
  short* AOb = (short*)ws;  // total ws use: 64 MiB

  k_prep<<<8192, 256, 0, stream>>>(x, xb, Wq, Wk, Wv, Wo, Wt);
  k_qkv<<<5888, 256, 0, stream>>>(xb, Wt, bq, bk, bv, Qb, Kb, Vtb, kc, vc);
  k_attn_expand<<<10752, 256, 0, stream>>>(Qb, Kb, Vtb, AOb, kc, kF, vc, vF);
  k_gemm<<<dim3(8, 32), 256, 0, stream>>>(AOb, Wt + (size_t)3 * DM * DM, bo, out);
}

// Round 7
// 271.091 us; speedup vs baseline: 1.4260x; 1.4260x over previous
//
#include <hip/hip_runtime.h>
#include <hip/hip_bf16.h>
#include <cstdint>
#include <cstddef>

#define DM 1024
#define NH 16
#define DH 64
#define BB 2
#define TQ 2048
#define TCACHE 2048
#define TKTOT 4096
#define MROWS 4096

typedef __attribute__((ext_vector_type(8))) short bf16x8;
typedef __attribute__((ext_vector_type(4))) float f32x4;
typedef __attribute__((ext_vector_type(16))) float f32x16;

// pack two f32 -> two bf16 in one dword (RNE). gfx950 has NO builtin for
// cvt_pk_bf16 (m240) -- must use inline asm; the software path is ~12 VALU ops.
__device__ __forceinline__ unsigned pk2(float a, float b) {
  unsigned r;
  asm("v_cvt_pk_bf16_f32 %0, %1, %2" : "=v"(r) : "v"(a), "v"(b));
  return r;
}

__device__ __forceinline__ short f2bf(float f) {
  return (short)(unsigned short)pk2(f, f);
}

__device__ __forceinline__ uint2 pk4(float x, float y, float z, float w) {
  uint2 r;
  r.x = pk2(x, y);
  r.y = pk2(z, w);
  return r;
}

__device__ __forceinline__ float bf2f(short s) {
  union { unsigned u; float f; } v;
  v.u = ((unsigned)(unsigned short)s) << 16;
  return v.f;
}

__device__ __forceinline__ float exp2fast(float x) {
#if __has_builtin(__builtin_amdgcn_exp2f)
  return __builtin_amdgcn_exp2f(x);
#else
  return exp2f(x);
#endif
}

// v_permlane32_swap_b32: a' = {a.lo, b.lo}, b' = {a.hi, b.hi} (lane halves)
__device__ __forceinline__ void plswap(unsigned& a, unsigned& b) {
  asm volatile("v_permlane32_swap_b32 %0, %1" : "+v"(a), "+v"(b));
}

// async global->LDS, 16B/lane. COALESCED by construction (lane i -> base+16i)
// AND latency-hidden via double-buffer. R6 lesson: per-lane direct global
// fragment reads (stride-128B, 16B/lane) quadruple cache-line traffic and
// collapse all pipes -- LDS staging is for coalescing, not just latency.
__device__ __forceinline__ void gld_lds16(const short* g, short* l) {
  __builtin_amdgcn_global_load_lds(
      (const __attribute__((address_space(1))) void*)((uintptr_t)g),
      (__attribute__((address_space(3))) void*)((uintptr_t)l), 16, 0, 0);
}

// ---------- prep kernel: x conversion + W transpose only ----------
// roles by linear blockIdx.x (all 256 threads):
//   [0,4096)      cvt_x:       x f32 -> xb bf16
//   [4096,8192)   transpose_w: W f32 [K][N] -> Wt bf16 [N][K] (4 weights)
__global__ __launch_bounds__(256) void k_prep(
    const float* __restrict__ x, short* __restrict__ xb,
    const float* __restrict__ W0, const float* __restrict__ W1,
    const float* __restrict__ W2, const float* __restrict__ W3,
    short* __restrict__ Wt) {
  __shared__ short lds[32 * 33];
  const int bid = (int)blockIdx.x;
  if (bid < 4096) {
    const size_t i = (size_t)bid * 256 + threadIdx.x;
    const float4 v = ((const float4*)x)[i];
    *(uint2*)(((short4*)xb) + i) = pk4(v.x, v.y, v.z, v.w);
  } else {
    const int local = bid - 4096;
    const int bx = local & 31, by = (local >> 5) & 31, bz = local >> 10;
    short (*tile)[33] = (short(*)[33])lds;
    const float* W = (bz == 0) ? W0 : (bz == 1) ? W1 : (bz == 2) ? W2 : W3;
    short* dst = Wt + (size_t)bz * DM * DM;
    const int k0 = by * 32, n0 = bx * 32;
    const int tx = threadIdx.x & 31, ty = threadIdx.x >> 5;
#pragma unroll
    for (int r = 0; r < 4; r++) {
      const int k = ty + r * 8;
      tile[k][tx] = f2bf(W[(size_t)(k0 + k) * DM + n0 + tx]);
    }
    __syncthreads();
#pragma unroll
    for (int r = 0; r < 4; r++) {
      const int n = ty + r * 8;
      dst[(size_t)(n0 + n) * DM + k0 + tx] = tile[tx][n];
    }
  }
}

// ---------- fused QKV GEMM + KV-cache conversion ----------
// roles by blockIdx.x:
//   [0,768)       GEMM 128x128, BK=32, dbuf global_load_lds (z = bid>>8: Q/K/V)
//   [768,4864)    kc f32 -> Kb bf16 (cache part)
//   [4864,5888)   vc f32 -> Vtb bf16 [dh][t] (cache part)
// copy blocks are pure streaming and backfill under the compute-bound GEMM
// blocks (3/CU), complementary-pipe trick.
__global__ __launch_bounds__(256) void k_qkv(
    const short* __restrict__ A, const short* __restrict__ Bt,
    const float* __restrict__ b0, const float* __restrict__ b1, const float* __restrict__ b2,
    short* __restrict__ Qb, short* __restrict__ Kb, short* __restrict__ Vtb,
    const float* __restrict__ kc, const float* __restrict__ vc) {
  __shared__ short SH[16384];  // 32KB: GEMM sA[2]+sB[2]; vc-copy tile
  const int bid = (int)blockIdx.x;
  if (bid < 768) {
    const int z = bid >> 8;
    const int by = (bid >> 3) & 31;
    const int bx = bid & 7;
    const short* Bz = Bt + (size_t)z * DM * DM;
    const float* bias = (z == 0) ? b0 : (z == 1 ? b1 : b2);

    const int m0 = by * 128;
    const int n0 = bx * 128;
    const int tid = threadIdx.x;
    const int wv = tid >> 6;
    const int lane = tid & 63;
    const int quad = lane >> 4;
    const int l16 = lane & 15;
    const int wm = (wv >> 1) * 64;
    const int wn = (wv & 1) * 64;

    const f32x4 zero = {0.f, 0.f, 0.f, 0.f};
    f32x4 acc[4][4];
#pragma unroll
    for (int i = 0; i < 4; i++)
#pragma unroll
      for (int j = 0; j < 4; j++) acc[i][j] = zero;

    const int sw = (quad ^ ((l16 >> 1) & 3)) << 4;
    const int afo = (wm + l16) * 64 + sw;
    const int bfo = (wn + l16) * 64 + sw;

#define STAGEG(k0_, b_)                                                              \
    do {                                                                             \
      _Pragma("unroll") for (int s = 0; s < 2; s++) {                                \
        const int c = tid + s * 256;                                                 \
        const int row = c >> 2, cs = c & 3;                                          \
        const int gc = cs ^ ((row >> 1) & 3);                                        \
        gld_lds16(A + (size_t)(m0 + row) * DM + (k0_) + gc * 8,                      \
                  SH + (b_) * 4096 + c * 8);                                         \
        gld_lds16(Bz + (size_t)(n0 + row) * DM + (k0_) + gc * 8,                     \
                  SH + 8192 + (b_) * 4096 + c * 8);                                  \
      }                                                                              \
    } while (0)

    STAGEG(0, 0);
    __syncthreads();
    int buf = 0;
    for (int k0 = 0; k0 < DM; k0 += 32) {
      if (k0 + 32 < DM) STAGEG(k0 + 32, buf ^ 1);
      const char* Ab = (const char*)SH + buf * 8192;
      const char* Bb = (const char*)SH + 16384 + buf * 8192;
      bf16x8 af[4], bfv[4];
#pragma unroll
      for (int i = 0; i < 4; i++) af[i] = *(const bf16x8*)(Ab + afo + i * 1024);
#pragma unroll
      for (int j = 0; j < 4; j++) bfv[j] = *(const bf16x8*)(Bb + bfo + j * 1024);
      __builtin_amdgcn_s_setprio(1);
#pragma unroll
      for (int i = 0; i < 4; i++)
#pragma unroll
        for (int j = 0; j < 4; j++)
          acc[i][j] = __builtin_amdgcn_mfma_f32_16x16x32_bf16(af[i], bfv[j], acc[i][j], 0, 0, 0);
      __builtin_amdgcn_s_setprio(0);
      __syncthreads();
      buf ^= 1;
    }
#undef STAGEG

#pragma unroll
    for (int i = 0; i < 4; i++) {
#pragma unroll
      for (int j = 0; j < 4; j++) {
        const int gn = n0 + wn + j * 16 + l16;
        const float bb = bias[gn];
#pragma unroll
        for (int r = 0; r < 4; r++) {
          const int gm = m0 + wm + i * 16 + quad * 4 + r;
          const float v = acc[i][j][r] + bb;
          const int b_ = gm >> 11, t = gm & 2047;
          const int h_ = gn >> 6, dh = gn & 63;
          if (z == 0) {
            // fold softmax scale AND log2(e): 0.125 * 1.4426950409
            Qb[(((size_t)(b_ * NH + h_)) * TQ + t) * DH + dh] = f2bf(v * 0.18033688011f);
          } else if (z == 1) {
            Kb[(((size_t)(b_ * NH + h_)) * TKTOT + TCACHE + t) * DH + dh] = f2bf(v);
          } else {
            Vtb[(((size_t)(b_ * NH + h_)) * DH + dh) * TKTOT + TCACHE + t] = f2bf(v);
          }
        }
      }
    }
  } else if (bid < 4864) {
    // kc copy role
    const size_t i = (size_t)(bid - 768) * 256 + threadIdx.x;
    const float4 v = ((const float4*)kc)[i];
    const size_t e = i * 4;
    const int dh = (int)(e & 63);
    const int t = (int)((e >> 6) & 2047);
    const int bh = (int)(e >> 17);
    *(uint2*)(Kb + ((size_t)bh * TKTOT + t) * DH + dh) = pk4(v.x, v.y, v.z, v.w);
  } else {
    // vc copy role (transpose to Vt[dh][t])
    const int local = bid - 4864;
    const int bh = local >> 5;
    const int t0 = (local & 31) * 64;
    short (*tile)[65] = (short(*)[65])SH;
    const int tx = threadIdx.x & 15, ty = threadIdx.x >> 4;
    const float* src = vc + ((size_t)bh * TCACHE + t0) * DH;
#pragma unroll
    for (int r = 0; r < 4; r++) {
      const int t = ty + r * 16;
      const float4 v = *(const float4*)(src + (size_t)t * DH + tx * 4);
      tile[tx * 4 + 0][t] = f2bf(v.x);
      tile[tx * 4 + 1][t] = f2bf(v.y);
      tile[tx * 4 + 2][t] = f2bf(v.z);
      tile[tx * 4 + 3][t] = f2bf(v.w);
    }
    __syncthreads();
    short* vt = Vtb + (size_t)bh * DH * TKTOT + t0;
#pragma unroll
    for (int r = 0; r < 4; r++) {
      const int dh = ty + r * 16;
      short4 o;
      o.x = tile[dh][tx * 4 + 0];
      o.y = tile[dh][tx * 4 + 1];
      o.z = tile[dh][tx * 4 + 2];
      o.w = tile[dh][tx * 4 + 3];
      *(short4*)(vt + (size_t)dh * TKTOT + tx * 4) = o;
    }
  }
}

// ---------- proj GEMM: out = AOb * Wo^T + bo (f32 output) ----------
// 64x128 tile, grid (8,64) = 512 blocks = 2/CU (the 128x128 version was
// 256 blocks = 1 block/CU = 1 wave/SIMD -- zero latency hiding).
__global__ __launch_bounds__(256) void k_proj(
    const short* __restrict__ A, const short* __restrict__ Bt,
    const float* __restrict__ bias, float* __restrict__ fdst) {
  __shared__ short sA[2][64 * 32];   // 2 x 4KB
  __shared__ short sB[2][128 * 32];  // 2 x 8KB

  const int m0 = blockIdx.y * 64;
  const int n0 = blockIdx.x * 128;
  const int tid = threadIdx.x;
  const int wv = tid >> 6;
  const int lane = tid & 63;
  const int quad = lane >> 4;
  const int l16 = lane & 15;
  const int wm = (wv >> 1) * 32;
  const int wn = (wv & 1) * 64;

  const f32x4 zero = {0.f, 0.f, 0.f, 0.f};
  f32x4 acc[2][4];
#pragma unroll
  for (int i = 0; i < 2; i++)
#pragma unroll
    for (int j = 0; j < 4; j++) acc[i][j] = zero;

  const int sw = (quad ^ ((l16 >> 1) & 3)) << 4;
  const int afo = (wm + l16) * 64 + sw;
  const int bfo = (wn + l16) * 64 + sw;

#define STAGEP(k0_, b_)                                                          \
  do {                                                                           \
    {                                                                            \
      const int c = tid;                                                         \
      const int row = c >> 2, cs = c & 3;                                        \
      const int gc = cs ^ ((row >> 1) & 3);                                      \
      gld_lds16(A + (size_t)(m0 + row) * DM + (k0_) + gc * 8, &sA[b_][c * 8]);   \
    }                                                                            \
    _Pragma("unroll") for (int s = 0; s < 2; s++) {                              \
      const int c = tid + s * 256;                                               \
      const int row = c >> 2, cs = c & 3;                                        \
      const int gc = cs ^ ((row >> 1) & 3);                                      \
      gld_lds16(Bt + (size_t)(n0 + row) * DM + (k0_) + gc * 8, &sB[b_][c * 8]);  \
    }                                                                            \
  } while (0)

  STAGEP(0, 0);
  __syncthreads();
  int buf = 0;
  for (int k0 = 0; k0 < DM; k0 += 32) {
    if (k0 + 32 < DM) STAGEP(k0 + 32, buf ^ 1);
    const char* Ab = (const char*)&sA[0][0] + buf * 4096;
    const char* Bb = (const char*)&sB[0][0] + buf * 8192;
    bf16x8 af[2], bfv[4];
#pragma unroll
    for (int i = 0; i < 2; i++) af[i] = *(const bf16x8*)(Ab + afo + i * 1024);
#pragma unroll
    for (int j = 0; j < 4; j++) bfv[j] = *(const bf16x8*)(Bb + bfo + j * 1024);
    __builtin_amdgcn_s_setprio(1);
#pragma unroll
    for (int i = 0; i < 2; i++)
#pragma unroll
      for (int j = 0; j < 4; j++)
        acc[i][j] = __builtin_amdgcn_mfma_f32_16x16x32_bf16(af[i], bfv[j], acc[i][j], 0, 0, 0);
    __builtin_amdgcn_s_setprio(0);
    __syncthreads();
    buf ^= 1;
  }
#undef STAGEP

#pragma unroll
  for (int i = 0; i < 2; i++) {
#pragma unroll
    for (int j = 0; j < 4; j++) {
      const int gn = n0 + wn + j * 16 + l16;
      const float bb = bias[gn];
#pragma unroll
      for (int r = 0; r < 4; r++) {
        const int gm = m0 + wm + i * 16 + quad * 4 + r;
        fdst[(size_t)gm * DM + gn] = acc[i][j][r] + bb;
      }
    }
  }
}

// ---------- fused attention + expand (R5-proven attention role) ----------
// roles by blockIdx.x:
//   [0,512)       flash attention, QBLK=128, NO split-K, LDS-staged dbuf K/V
//                 (coalesced global_load_lds + 1-tile prefetch), in-kernel
//                 normalize, bf16 AOb out. qx map pairs long+short per CU.
//   [512,8704)    expand_k: kF f32 from kc (cache, exact) / Kb bf16 (new)
//   [8704,10752)  expand_v: vF f32 from vc (cache) / Vtb transposed (new)
__global__ __launch_bounds__(256, 4) void k_attn_expand(
    const short* __restrict__ Qb, const short* __restrict__ Kb,
    const short* __restrict__ Vtb, short* __restrict__ AOb,
    const float* __restrict__ kc, float* __restrict__ kF,
    const float* __restrict__ vc, float* __restrict__ vF) {
  __shared__ short SH[16384];  // 32KB: attn sK[2][4096]+sV[2][4096]; expand tile

  const int bid = (int)blockIdx.x;
  if (bid < 512) {
    // ---------------- attention role ----------------
    const int y = bid >> 5;
    const int bh = bid & 31;
    const int qx = (y < 8) ? (15 - y) : (y - 8);
    const int q0 = qx * 128;
    const int tid = threadIdx.x;
    const int wq = tid >> 6;
    const int lane = tid & 63;
    const int l32 = lane & 31;
    const int h = lane >> 5;

    const int nkt = 2 * qx + 34;  // total key tiles for this q-block

    const short* Kg = Kb + (size_t)bh * TKTOT * DH;
    const short* Vtg = Vtb + (size_t)bh * DH * TKTOT;

    // staging source pointers (per-thread, kt-invariant part)
    const int c0 = tid, c1 = tid + 256;
    const int r0 = c0 >> 3, g0 = ((c0 & 7) ^ (r0 & 7)) * 8;
    const int r1 = c1 >> 3, g1 = ((c1 & 7) ^ (r1 & 7)) * 8;
    const short* Kst0 = Kg + (size_t)r0 * DH + g0;
    const short* Kst1 = Kg + (size_t)r1 * DH + g1;
    const short* Vst0 = Vtg + (size_t)r0 * TKTOT + g0;
    const short* Vst1 = Vtg + (size_t)r1 * TKTOT + g1;

    // Q fragments straight from global: B-operand, lane holds q=l32, k=8h+i
    const short* Qrow = Qb + ((size_t)bh * TQ + q0 + wq * 32 + l32) * DH;
    bf16x8 qf[4];
#pragma unroll
    for (int s = 0; s < 4; s++) qf[s] = *(const bf16x8*)(Qrow + s * 16 + h * 8);

    // kt-invariant LDS read offsets: row = (32*blk + l32), chunk c=2*ks+h, swz c^(row&7)
    const char* sKc = (const char*)SH;           // sK: bytes [0, 16384)
    const char* sVc = (const char*)SH + 16384;   // sV: bytes [16384, 32768)
    const int rx7 = l32 & 7;
    const int base0 = l32 * 128;
    const int base1 = base0 + 4096;
    int co[4];
#pragma unroll
    for (int ks = 0; ks < 4; ks++) co[ks] = ((2 * ks + h) ^ rx7) << 4;

    const f32x16 zerov = {0, 0, 0, 0, 0, 0, 0, 0, 0, 0, 0, 0, 0, 0, 0, 0};
    f32x16 of0 = zerov;
    f32x16 of1 = zerov;
    float la = 0.f, lb = 0.f, lc = 0.f, ld = 0.f;

#define STAGE(t_, b_)                                    \
    do {                                                 \
      const size_t koff = (size_t)(t_) * 64 * DH;        \
      const size_t voff = (size_t)(t_) * 64;             \
      short* dK = SH + (b_)*4096;                        \
      short* dV = SH + 8192 + (b_)*4096;                 \
      gld_lds16(Kst0 + koff, dK + c0 * 8);               \
      gld_lds16(Kst1 + koff, dK + c1 * 8);               \
      gld_lds16(Vst0 + voff, dV + c0 * 8);               \
      gld_lds16(Vst1 + voff, dV + c1 * 8);               \
    } while (0)

    STAGE(0, 0);
    __syncthreads();
    int buf = 0;

    for (int t = 0; t < nkt; t++) {
      if (t + 1 < nkt) STAGE(t + 1, buf ^ 1);
      const char* kb_ = sKc + buf * 8192;
      const char* vb_ = sVc + buf * 8192;

      // Sacc = K * Q^T : col(lane&31)=q, row(reg)=key = (r&3)+8*(r>>2)+4h (+32 blk1)
      f32x16 sacc0, sacc1;
      __builtin_amdgcn_s_setprio(1);
      {
        const bf16x8 kf0 = *(const bf16x8*)(kb_ + base0 + co[0]);
        const bf16x8 kf1 = *(const bf16x8*)(kb_ + base1 + co[0]);
        sacc0 = __builtin_amdgcn_mfma_f32_32x32x16_bf16(kf0, qf[0], zerov, 0, 0, 0);
        sacc1 = __builtin_amdgcn_mfma_f32_32x32x16_bf16(kf1, qf[0], zerov, 0, 0, 0);
      }
#pragma unroll
      for (int ks = 1; ks < 4; ks++) {
        const bf16x8 kf0 = *(const bf16x8*)(kb_ + base0 + co[ks]);
        const bf16x8 kf1 = *(const bf16x8*)(kb_ + base1 + co[ks]);
        sacc0 = __builtin_amdgcn_mfma_f32_32x32x16_bf16(kf0, qf[ks], sacc0, 0, 0, 0);
        sacc1 = __builtin_amdgcn_mfma_f32_32x32x16_bf16(kf1, qf[ks], sacc1, 0, 0, 0);
      }
      __builtin_amdgcn_s_setprio(0);

      if (t >= nkt - 2) {  // diagonal spans 2 tiles at QBLK=128
        const int qgl = q0 + wq * 32 + l32 + TCACHE;
        const int kb0 = t * 64 + 4 * h;
#pragma unroll
        for (int r = 0; r < 16; r++) {
          const int key = kb0 + (r & 3) + 8 * (r >> 2);
          if (key > qgl) sacc0[r] = -1e30f;
          if (key + 32 > qgl) sacc1[r] = -1e30f;
        }
      }
#pragma unroll
      for (int r = 0; r < 16; r++) {
        const float e0 = exp2fast(sacc0[r]);
        const float e1 = exp2fast(sacc1[r]);
        sacc0[r] = e0;
        sacc1[r] = e1;
        if ((r & 3) == 0) la += e0 + e1;
        else if ((r & 3) == 1) lb += e0 + e1;
        else if ((r & 3) == 2) lc += e0 + e1;
        else ld += e0 + e1;
      }

      // pack + lane-half swap -> PV A-operand: row(lane&31)=q, k=8h+i per kstep
      bf16x8 pa[4];
#pragma unroll
      for (int s = 0; s < 4; s++) {
        const int o = (s & 1) * 8;
        unsigned w0, w1, w2, w3;
        if (s < 2) {
          w0 = pk2(sacc0[o + 0], sacc0[o + 1]);
          w1 = pk2(sacc0[o + 2], sacc0[o + 3]);
          w2 = pk2(sacc0[o + 4], sacc0[o + 5]);
          w3 = pk2(sacc0[o + 6], sacc0[o + 7]);
        } else {
          w0 = pk2(sacc1[o + 0], sacc1[o + 1]);
          w1 = pk2(sacc1[o + 2], sacc1[o + 3]);
          w2 = pk2(sacc1[o + 4], sacc1[o + 5]);
          w3 = pk2(sacc1[o + 6], sacc1[o + 7]);
        }
        plswap(w0, w2);  // w0={lo,lo}, w2={hi,hi}
        plswap(w1, w3);
        union { unsigned u[4]; bf16x8 v; } pu;
        pu.u[0] = w0; pu.u[1] = w1; pu.u[2] = w2; pu.u[3] = w3;
        pa[s] = pu.v;
      }

      // O[q][dh] += P * V : B=V[k][dh] from Vt LDS
      __builtin_amdgcn_s_setprio(1);
#pragma unroll
      for (int ks = 0; ks < 4; ks++) {
        const bf16x8 vf0 = *(const bf16x8*)(vb_ + base0 + co[ks]);
        const bf16x8 vf1 = *(const bf16x8*)(vb_ + base1 + co[ks]);
        of0 = __builtin_amdgcn_mfma_f32_32x32x16_bf16(pa[ks], vf0, of0, 0, 0, 0);
        of1 = __builtin_amdgcn_mfma_f32_32x32x16_bf16(pa[ks], vf1, of1, 0, 0, 0);
      }
      __builtin_amdgcn_s_setprio(0);
      __syncthreads();
      buf ^= 1;
    }
#undef STAGE

    // ---- in-kernel normalize + bf16 output ----
    float* sLf = (float*)SH;
    const float l_lane = (la + lb) + (lc + ld);
    const float l_tot = l_lane + __shfl_xor(l_lane, 32);
    if (h == 0) sLf[wq * 32 + l32] = l_tot;
    const int b_ = bh >> 4, h_ = bh & 15;
#pragma unroll
    for (int r = 0; r < 16; r++) {
      const int row = (r & 3) + 8 * (r >> 2) + 4 * h;  // q within the wave's 32
      const float inv = 1.f / sLf[wq * 32 + row];
      const int qg = q0 + wq * 32 + row;
      short* d = AOb + ((size_t)(b_ * TQ + qg)) * DM + h_ * 64;
      d[l32] = f2bf(of0[r] * inv);
      d[32 + l32] = f2bf(of1[r] * inv);
    }
  } else if (bid < 8704) {
    // ---------------- expand_k role ----------------
    const size_t f4 = (size_t)(bid - 512) * 256 + threadIdx.x;
    const size_t e = f4 * 4;
    const int t = (int)((e >> 6) & 4095);
    float4 v;
    if (t < TCACHE) {
      const int dh = (int)(e & 63);
      const int bh = (int)(e >> 18);
      v = *(const float4*)(kc + ((size_t)(bh * TCACHE + t)) * DH + dh);
    } else {
      const short4 s = *(const short4*)(Kb + e);
      v.x = bf2f(s.x); v.y = bf2f(s.y); v.z = bf2f(s.z); v.w = bf2f(s.w);
    }
    *(float4*)(kF + e) = v;
  } else {
    // ---------------- expand_v role ----------------
    const int local = bid - 8704;
    const int tt = local & 63, bh = local >> 6;
    short* tile = SH;  // [64][72]
    if (tt < 32) {
#pragma unroll
      for (int k2 = 0; k2 < 4; k2++) {
        const int f = threadIdx.x + k2 * 256;
        const int trow = f >> 4, dh4 = f & 15;
        const size_t si = ((size_t)(bh * TCACHE) + tt * 64 + trow) * DH + dh4 * 4;
        const size_t di = ((size_t)(bh * TKTOT) + tt * 64 + trow) * DH + dh4 * 4;
        *(float4*)(vF + di) = *(const float4*)(vc + si);
      }
    } else {
      const int t0 = tt * 64;
#pragma unroll
      for (int k2 = 0; k2 < 4; k2++) {
        const int f = threadIdx.x + k2 * 256;
        const int dh = f >> 4, tc4 = f & 15;
        const short4 s = *(const short4*)(Vtb + ((size_t)(bh * DH + dh)) * TKTOT + t0 + tc4 * 4);
        *(short4*)(&tile[dh * 72 + tc4 * 4]) = s;
      }
      __syncthreads();
#pragma unroll
      for (int k2 = 0; k2 < 4; k2++) {
        const int f = threadIdx.x + k2 * 256;
        const int trow = f >> 4, dh4 = f & 15;
        float4 v;
        v.x = bf2f(tile[(dh4 * 4 + 0) * 72 + trow]);
        v.y = bf2f(tile[(dh4 * 4 + 1) * 72 + trow]);
        v.z = bf2f(tile[(dh4 * 4 + 2) * 72 + trow]);
        v.w = bf2f(tile[(dh4 * 4 + 3) * 72 + trow]);
        *(float4*)(vF + ((size_t)(bh * TKTOT) + t0 + trow) * DH + dh4 * 4) = v;
      }
    }
  }
}

// ---------- host ----------

extern "C" void kernel_launch(void* const* d_in, const int* in_sizes, int n_in,
                              void* d_out, int out_size, void* d_ws, size_t ws_size,
                              hipStream_t stream) {
  const float* x = (const float*)d_in[0];
  const float* kc = (const float*)d_in[1];
  const float* vc = (const float*)d_in[2];
  const float* Wq = (const float*)d_in[3];
  const float* bq = (const float*)d_in[4];
  const float* Wk = (const float*)d_in[5];
  const float* bk = (const float*)d_in[6];
  const float* Wv = (const float*)d_in[7];
  const float* bv = (const float*)d_in[8];
  const float* Wo = (const float*)d_in[9];
  const float* bo = (const float*)d_in[10];

  float* out = (float*)d_out;
  float* kF = out + (size_t)BB * TQ * DM;          // k output region (33.55 MB)
  float* vF = kF + (size_t)BB * NH * TKTOT * DH;   // v output region (33.55 MB)

  char* ws = (char*)d_ws;
  short* xb = (short*)ws;   ws += (size_t)MROWS * DM * 2;
  short* Wt = (short*)ws;   ws += (size_t)4 * DM * DM * 2;
  short* Qb = (short*)ws;   ws += (size_t)BB * NH * TQ * DH * 2;
  short* Kb = (short*)ws;   ws += (size_t)BB * NH * TKTOT * DH * 2;
  short* Vtb = (short*)ws;  ws += (size_t)BB * NH * TKTOT * DH * 2;
  short* AOb = (short*)ws;  // total ws use: 64 MiB

  k_prep<<<8192, 256, 0, stream>>>(x, xb, Wq, Wk, Wv, Wo, Wt);
  k_qkv<<<5888, 256, 0, stream>>>(xb, Wt, bq, bk, bv, Qb, Kb, Vtb, kc, vc);
  k_attn_expand<<<10752, 256, 0, stream>>>(Qb, Kb, Vtb, AOb, kc, kF, vc, vF);
  k_proj<<<dim3(8, 64), 256, 0, stream>>>(AOb, Wt + (size_t)3 * DM * DM, bo, out);
}